// Round 7
// baseline (122.788 us; speedup 1.0000x reference)
//
#include <hip/hip_runtime.h>
#include <math.h>

// ---------------------------------------------------------------------------
// B=32 queries [B,512] fp32 vs N=20000 keys [N,512] fp32.
// scores = Q K^T / sqrt(512); softmax over N; top-8; gather values rows.
// Output = [B*8 weights f32] ++ [B*8 * 10240 values f32].
//
// R7 (= R6 with compile fixes): ONE plain kernel (256 blocks x 256 thr,
// 1 block/CU — co-residency proven by R4's cooperative launch) with a
// HAND-ROLLED grid barrier (agent-scope atomic arrive + acquire spin +
// s_sleep backoff; counter zeroed per launch by captured hipMemsetAsync).
// R4 showed driver grid.sync costs ~25-35us each; work models at ~17us.
//  P0 qconv:   per-block q -> bf16 into padded LDS (read from L2/L3)
//  P1 scores:  bf16 MFMA, keys streamed from HBM, A-frags from LDS
//  P2 part:    256 blocks == (row,chunk): online max/sum-exp + top-8
//  P3 final:   blocks 0-31 wave 0: merge 64 cands -> top-12 -> EXACT fp32
//              rescore -> weights + indices
//  P4 gather:  2560 x 4KB segments, 10 per block
// ---------------------------------------------------------------------------

#define TOPK 8
#define DKD 512
#define NCHUNK 8
#define GRID 256

typedef __attribute__((ext_vector_type(8))) short short8;
typedef __attribute__((ext_vector_type(4))) float f32x4;

__device__ inline unsigned short f2bf(float x) {
    unsigned int u = __float_as_uint(x);
    u = (u + 0x7fffu + ((u >> 16) & 1u)) >> 16;   // RNE to bf16
    return (unsigned short)u;
}

// comparator everywhere: value desc, index asc (matches lax.top_k ties)
__device__ inline void wave_argmax(float& v, int& i) {
    #pragma unroll
    for (int off = 1; off < 64; off <<= 1) {
        float ov = __shfl_xor(v, off);
        int   oi = __shfl_xor(i, off);
        if (ov > v || (ov == v && oi < i)) { v = ov; i = oi; }
    }
}

// lightweight grid barrier: counter starts at 0 each launch (memset node);
// barrier j spins until count >= 256*(j+1). Release-add publishes this
// block's writes (L2 writeback at agent scope); acquire-load invalidates
// stale lines on the reader side. SLP must be a literal (s_sleep constraint).
template <int SLP>
__device__ inline void grid_barrier(unsigned* cell, unsigned target) {
    __syncthreads();                       // drains block's vmem (waitcnt+barrier)
    if (threadIdx.x == 0) {
        __hip_atomic_fetch_add(cell, 1u, __ATOMIC_RELEASE, __HIP_MEMORY_SCOPE_AGENT);
        while (__hip_atomic_load(cell, __ATOMIC_ACQUIRE, __HIP_MEMORY_SCOPE_AGENT) < target) {
            __builtin_amdgcn_s_sleep(SLP);
        }
    }
    __syncthreads();
}

__global__ __launch_bounds__(256) void fused_kernel(
    const float* __restrict__ q, const float* __restrict__ keys,
    const float* __restrict__ values,
    float* __restrict__ scores, float* __restrict__ pm, float* __restrict__ ps,
    float* __restrict__ cv, int* __restrict__ ci, int* __restrict__ tidx,
    unsigned* __restrict__ barcell,
    float* __restrict__ out_w, float* __restrict__ out_v,
    int N, int LDV)
{
    const int bid  = blockIdx.x;
    const int tid  = threadIdx.x;
    const int lane = tid & 63;
    const int wid  = tid >> 6;
    const float scale = 0.04419417382415922f;   // 1/sqrt(512)

    __shared__ short qs[32][DKD + 8];           // +8 pad: 2-way LDS conflict (free)
    __shared__ float lm[4], ls[4], lcv[4][TOPK];
    __shared__ int   lci[4][TOPK];

    // ---------------- P0: q -> bf16 into LDS (per block, redundant) ---------
    #pragma unroll
    for (int i = 0; i < 16; ++i) {
        const int idx = i * 256 + tid;          // 0..4095 float4s
        const int row = idx >> 7;               // 128 float4 per row
        const int c4  = idx & 127;
        float4 v = *reinterpret_cast<const float4*>(&q[row * DKD + c4 * 4]);
        ushort4 h;
        h.x = f2bf(v.x); h.y = f2bf(v.y); h.z = f2bf(v.z); h.w = f2bf(v.w);
        *reinterpret_cast<ushort4*>(&qs[row][c4 * 4]) = h;
    }
    __syncthreads();

    // ---------------- P1: approx scores via bf16 MFMA -----------------------
    {
        const int col = lane & 15;              // key within tile / q-row in frags
        const int kg  = lane >> 4;              // k-chunk group 0..3
        const int ntiles = (N + 15) / 16;       // 1250

        for (int tile = bid * 4 + wid; tile < ntiles; tile += GRID * 4) {
            const int n0 = tile * 16;
            f32x4 acc0 = {0.f, 0.f, 0.f, 0.f};
            f32x4 acc1 = {0.f, 0.f, 0.f, 0.f};

            int nrow = n0 + col;
            const bool valid = (nrow < N);
            if (!valid) nrow = N - 1;           // clamp loads, skip stores
            const float* krow = keys + (size_t)nrow * DKD + kg * 8;
            const short* s0 = &qs[col][kg * 8];
            const short* s1 = &qs[col + 16][kg * 8];

            #pragma unroll 4
            for (int ks = 0; ks < 16; ++ks) {
                const int d = ks * 32;
                float4 ka = *reinterpret_cast<const float4*>(krow + d);
                float4 kb = *reinterpret_cast<const float4*>(krow + d + 4);
                short8 fh;
                fh[0] = (short)f2bf(ka.x); fh[1] = (short)f2bf(ka.y);
                fh[2] = (short)f2bf(ka.z); fh[3] = (short)f2bf(ka.w);
                fh[4] = (short)f2bf(kb.x); fh[5] = (short)f2bf(kb.y);
                fh[6] = (short)f2bf(kb.z); fh[7] = (short)f2bf(kb.w);
                short8 a0 = *reinterpret_cast<const short8*>(s0 + d);
                short8 a1 = *reinterpret_cast<const short8*>(s1 + d);
                acc0 = __builtin_amdgcn_mfma_f32_16x16x32_bf16(a0, fh, acc0, 0, 0, 0);
                acc1 = __builtin_amdgcn_mfma_f32_16x16x32_bf16(a1, fh, acc1, 0, 0, 0);
            }

            // D layout (m89-verified): col = lane&15, row = (lane>>4)*4 + reg
            if (valid) {
                #pragma unroll
                for (int j = 0; j < 4; ++j) {
                    const int r = kg * 4 + j;
                    scores[(size_t)r * N + n0 + col]        = acc0[j] * scale;
                    scores[(size_t)(r + 16) * N + n0 + col] = acc1[j] * scale;
                }
            }
        }
    }
    grid_barrier<8>(barcell, 256u);

    // ---------------- P2: per (row, chunk) online max/sum-exp + top-8 -------
    {
        const int b = bid >> 3, c = bid & 7;
        const int chunk = N / NCHUNK;                  // 2500
        const float* base = scores + (size_t)b * N + c * chunk;
        const int i0 = c * chunk;
        const int n4 = chunk >> 2;                     // 625

        float m = -INFINITY, s = 0.0f;
        float v[TOPK];
        int   j[TOPK];
        #pragma unroll
        for (int k = 0; k < TOPK; ++k) { v[k] = -INFINITY; j[k] = 0x7fffffff; }

        for (int i = tid; i < n4; i += 256) {
            float4 x4 = reinterpret_cast<const float4*>(base)[i];
            float xs[4] = {x4.x, x4.y, x4.z, x4.w};
            #pragma unroll
            for (int e = 0; e < 4; ++e) {
                const float x = xs[e];
                const int  gi = i0 + i * 4 + e;
                const float nm = fmaxf(m, x);
                s = s * __expf(m - nm) + __expf(x - nm);
                m = nm;
                if (x > v[TOPK - 1]) {
                    bool g[TOPK];
                    #pragma unroll
                    for (int k = 0; k < TOPK; ++k) g[k] = (x > v[k]);
                    #pragma unroll
                    for (int k = TOPK - 1; k >= 1; --k) {
                        v[k] = g[k] ? (g[k - 1] ? v[k - 1] : x) : v[k];
                        j[k] = g[k] ? (g[k - 1] ? j[k - 1] : gi) : j[k];
                    }
                    v[0] = g[0] ? x : v[0];
                    j[0] = g[0] ? gi : j[0];
                }
            }
        }

        // wave-level (m,s) combine
        #pragma unroll
        for (int off = 1; off < 64; off <<= 1) {
            float om = __shfl_xor(m, off), os = __shfl_xor(s, off);
            float M2 = fmaxf(m, om);
            s = s * __expf(m - M2) + os * __expf(om - M2);
            m = M2;
        }

        // wave-level top-8 merge: 8 selection rounds over lanes' sorted lists
        float selv = 0.f; int seli = 0;
        #pragma unroll
        for (int r = 0; r < TOPK; ++r) {
            float mv = v[0]; int mi = j[0];
            wave_argmax(mv, mi);
            if (v[0] == mv && j[0] == mi) {            // I won: pop my head
                #pragma unroll
                for (int k = 0; k < TOPK - 1; ++k) { v[k] = v[k + 1]; j[k] = j[k + 1]; }
                v[TOPK - 1] = -INFINITY; j[TOPK - 1] = 0x7fffffff;
            }
            if (lane == r) { selv = mv; seli = mi; }
        }

        if (lane == 0) { lm[wid] = m; ls[wid] = s; }
        if (lane < TOPK) { lcv[wid][lane] = selv; lci[wid][lane] = seli; }
        __syncthreads();

        if (wid == 0) {
            if (lane == 0) {
                float M = lm[0], S = ls[0];
                #pragma unroll
                for (int cc = 1; cc < 4; ++cc) {
                    float M2 = fmaxf(M, lm[cc]);
                    S = S * __expf(M - M2) + ls[cc] * __expf(lm[cc] - M2);
                    M = M2;
                }
                pm[bid] = M; ps[bid] = S;
            }
            float vv = (lane < 32) ? lcv[lane >> 3][lane & 7] : -INFINITY;
            int   ii = (lane < 32) ? lci[lane >> 3][lane & 7] : 0x7fffffff;
            #pragma unroll
            for (int r = 0; r < TOPK; ++r) {
                float mv = vv; int mi = ii;
                wave_argmax(mv, mi);
                if (vv == mv && ii == mi) vv = -INFINITY;
                if (lane == r) { cv[bid * TOPK + r] = mv; ci[bid * TOPK + r] = mi; }
            }
        }
    }
    grid_barrier<16>(barcell, 512u);

    // ---------------- P3: final rescore + weights (blocks 0-31, wave 0) -----
    if (bid < 32 && wid == 0) {
        const int b = bid;
        float M = -INFINITY;
        #pragma unroll
        for (int c = 0; c < NCHUNK; ++c) M = fmaxf(M, pm[b * NCHUNK + c]);
        float S = 0.f;
        #pragma unroll
        for (int c = 0; c < NCHUNK; ++c)
            S += ps[b * NCHUNK + c] * __expf(pm[b * NCHUNK + c] - M);

        // 64 candidates, select approx top-12
        float vv = cv[b * 64 + lane];
        int   ii = ci[b * 64 + lane];
        int   si = 0x7fffffff;
        #pragma unroll
        for (int r = 0; r < 12; ++r) {
            float mv = vv; int mi = ii;
            wave_argmax(mv, mi);
            if (vv == mv && ii == mi) vv = -INFINITY;
            if (lane == r) si = mi;
        }

        // exact fp32 rescore of the 12 candidates
        float4 qa = *reinterpret_cast<const float4*>(q + (size_t)b * DKD + lane * 8);
        float4 qb = *reinterpret_cast<const float4*>(q + (size_t)b * DKD + lane * 8 + 4);
        float exv = -INFINITY;
        #pragma unroll
        for (int r = 0; r < 12; ++r) {
            const int cand = __shfl(si, r);
            const float* kr = keys + (size_t)cand * DKD + lane * 8;
            float4 k1 = *reinterpret_cast<const float4*>(kr);
            float4 k2 = *reinterpret_cast<const float4*>(kr + 4);
            float p = qa.x * k1.x + qa.y * k1.y + qa.z * k1.z + qa.w * k1.w
                    + qb.x * k2.x + qb.y * k2.y + qb.z * k2.z + qb.w * k2.w;
            #pragma unroll
            for (int off = 1; off < 64; off <<= 1) p += __shfl_xor(p, off);
            if (lane == r) exv = p * scale;
        }

        // exact top-8 of 12, emit weights (max M cancels num/denom)
        float fv = (lane < 12) ? exv : -INFINITY;
        int   fi = (lane < 12) ? si : 0x7fffffff;
        #pragma unroll
        for (int r = 0; r < TOPK; ++r) {
            float mv = fv; int mi = fi;
            wave_argmax(mv, mi);
            if (fv == mv && fi == mi) fv = -INFINITY;
            if (lane == r) {
                out_w[b * TOPK + r] = __expf(mv - M) / S;
                tidx[b * TOPK + r]  = mi;
            }
        }
    }
    grid_barrier<32>(barcell, 768u);

    // ---------------- P4: gather (2560 x 4KB segments, 10 per block) --------
    {
        #pragma unroll
        for (int i = 0; i < 10; ++i) {
            const int s  = bid + i * GRID;             // 0..2559
            const int bk = s / 10;
            const int pt = s - bk * 10;
            const int id = tidx[bk];
            const float4* src = reinterpret_cast<const float4*>(
                values + (size_t)id * LDV + (size_t)pt * 1024);
            float4* dst = reinterpret_cast<float4*>(
                out_v + (size_t)bk * LDV + (size_t)pt * 1024);
            dst[tid] = src[tid];
        }
    }
}

extern "C" void kernel_launch(void* const* d_in, const int* in_sizes, int n_in,
                              void* d_out, int out_size, void* d_ws, size_t ws_size,
                              hipStream_t stream) {
    const float* q      = (const float*)d_in[0];
    const float* keys   = (const float*)d_in[1];
    const float* values = (const float*)d_in[2];

    const int B   = in_sizes[0] / DKD;                 // 32
    const int N   = in_sizes[1] / DKD;                 // 20000
    const int LDV = (int)((long long)in_sizes[2] / N); // 10240

    float* out   = (float*)d_out;
    float* out_w = out;
    float* out_v = out + (size_t)B * TOPK;

    char* wsb = (char*)d_ws;
    size_t off = 0;
    float* scores = (float*)(wsb + off); off += (size_t)B * N * sizeof(float);
    float* pm = (float*)(wsb + off); off += (size_t)B * NCHUNK * sizeof(float);
    float* ps = (float*)(wsb + off); off += (size_t)B * NCHUNK * sizeof(float);
    float* cv = (float*)(wsb + off); off += (size_t)B * NCHUNK * TOPK * sizeof(float);
    int*   ci = (int*)(wsb + off);   off += (size_t)B * NCHUNK * TOPK * sizeof(int);
    int*   tidx = (int*)(wsb + off); off += (size_t)B * TOPK * sizeof(int);
    unsigned* barcell = (unsigned*)(wsb + off); off += 256;  // barrier counter

    // zero the barrier counter every launch (captured as a memset node)
    (void)hipMemsetAsync(barcell, 0, sizeof(unsigned), stream);

    fused_kernel<<<GRID, 256, 0, stream>>>(
        q, keys, values, scores, pm, ps, cv, ci, tidx, barcell,
        out_w, out_v, N, LDV);
}

// Round 8
// 48.685 us; speedup vs baseline: 2.5221x; 2.5221x over previous
//
#include <hip/hip_runtime.h>
#include <math.h>

// ---------------------------------------------------------------------------
// B=32 queries [B,512] fp32 vs N=20000 keys [N,512] fp32.
// scores = Q K^T / sqrt(512); softmax over N; top-8; gather values rows.
// Output = [B*8 weights f32] ++ [B*8 * 10240 values f32].
//
// R8: 3 kernels, NO grid sync (R4/R7: any grid-wide sync costs 30+us).
// Block-scope fusion: each block's 64 keys are a complete chunk, so the
// scores->reduction boundary is just __syncthreads.
//  K1 score_part: q->bf16 LDS + bf16 MFMA (R7-proven interior) -> scores in
//     LDS [32][65] -> per-row (m, sum-exp, top-8 of 64) partials (72B/row).
//     Deletes the 2.56MB scores buffer and two kernel launches vs R3.
//  K2 row_merge:  per row: merge 313 tile partials (coalesced), top-12,
//     EXACT fp32 rescore, weights + indices (R5-proven merge/rescore code).
//  K3 gather:     values[idx] rows, 4 blocks/row (proven).
// ---------------------------------------------------------------------------

#define TOPK 8
#define DKD 512
#define NEG  -1.0e30f

typedef __attribute__((ext_vector_type(8))) short short8;
typedef __attribute__((ext_vector_type(4))) float f32x4;

__device__ inline unsigned short f2bf(float x) {
    unsigned int u = __float_as_uint(x);
    u = (u + 0x7fffu + ((u >> 16) & 1u)) >> 16;   // RNE to bf16
    return (unsigned short)u;
}

// comparator everywhere: value desc, index asc (matches lax.top_k ties)
__device__ inline void wave_argmax(float& v, int& i) {
    #pragma unroll
    for (int off = 1; off < 64; off <<= 1) {
        float ov = __shfl_xor(v, off);
        int   oi = __shfl_xor(i, off);
        if (ov > v || (ov == v && oi < i)) { v = ov; i = oi; }
    }
}

// sorted-desc top-8 insert (boolean network, strict > keeps earlier index on ties)
__device__ inline void top8_insert(float (&v)[8], int (&ji)[8], float x, int gi) {
    if (x > v[7]) {
        bool g[8];
        #pragma unroll
        for (int k = 0; k < 8; ++k) g[k] = (x > v[k]);
        #pragma unroll
        for (int k = 7; k >= 1; --k) {
            v[k]  = g[k] ? (g[k - 1] ? v[k - 1] : x)  : v[k];
            ji[k] = g[k] ? (g[k - 1] ? ji[k - 1] : gi) : ji[k];
        }
        v[0]  = g[0] ? x  : v[0];
        ji[0] = g[0] ? gi : ji[0];
    }
}

// ---- K1: MFMA scores (64 keys/block) + in-block per-row partials ----------
__global__ __launch_bounds__(256) void score_part_kernel(
    const float* __restrict__ q, const float* __restrict__ keys,
    float* __restrict__ pmg, float* __restrict__ psg,
    float* __restrict__ cvg, int* __restrict__ cig, int N, int NTB)
{
    const int tid  = threadIdx.x;
    const int lane = tid & 63;
    const int wid  = tid >> 6;
    const float scale = 0.04419417382415922f;   // 1/sqrt(512)

    __shared__ short qs[32][DKD + 8];   // bf16 q, +8 pad (2-way banks = free)
    __shared__ float S[32][65];         // scores tile, +1 pad

    // ---- P0: q -> bf16 into LDS (64KB read, 1x per block) ----
    #pragma unroll
    for (int i = 0; i < 16; ++i) {
        const int idx = i * 256 + tid;          // 0..4095 float4s
        const int row = idx >> 7;               // 128 float4 per row
        const int c4  = idx & 127;
        float4 v = *reinterpret_cast<const float4*>(&q[row * DKD + c4 * 4]);
        ushort4 h;
        h.x = f2bf(v.x); h.y = f2bf(v.y); h.z = f2bf(v.z); h.w = f2bf(v.w);
        *reinterpret_cast<ushort4*>(&qs[row][c4 * 4]) = h;
    }
    __syncthreads();

    // ---- P1: 16-key MFMA tile per wave (R7-proven interior) ----
    {
        const int col = lane & 15;
        const int kg  = lane >> 4;
        const int n0  = blockIdx.x * 64 + wid * 16;

        f32x4 acc0 = {0.f, 0.f, 0.f, 0.f};
        f32x4 acc1 = {0.f, 0.f, 0.f, 0.f};

        int nrow = n0 + col;
        const bool valid = (nrow < N);
        if (!valid) nrow = N - 1;               // clamp loads
        const float* krow = keys + (size_t)nrow * DKD + kg * 8;
        const short* s0 = &qs[col][kg * 8];
        const short* s1 = &qs[col + 16][kg * 8];

        #pragma unroll 4
        for (int ks = 0; ks < 16; ++ks) {
            const int d = ks * 32;
            float4 ka = *reinterpret_cast<const float4*>(krow + d);
            float4 kb = *reinterpret_cast<const float4*>(krow + d + 4);
            short8 fh;
            fh[0] = (short)f2bf(ka.x); fh[1] = (short)f2bf(ka.y);
            fh[2] = (short)f2bf(ka.z); fh[3] = (short)f2bf(ka.w);
            fh[4] = (short)f2bf(kb.x); fh[5] = (short)f2bf(kb.y);
            fh[6] = (short)f2bf(kb.z); fh[7] = (short)f2bf(kb.w);
            short8 a0 = *reinterpret_cast<const short8*>(s0 + d);
            short8 a1 = *reinterpret_cast<const short8*>(s1 + d);
            acc0 = __builtin_amdgcn_mfma_f32_16x16x32_bf16(a0, fh, acc0, 0, 0, 0);
            acc1 = __builtin_amdgcn_mfma_f32_16x16x32_bf16(a1, fh, acc1, 0, 0, 0);
        }

        // D layout (m89-verified): col = lane&15, row = (lane>>4)*4 + reg
        #pragma unroll
        for (int j = 0; j < 4; ++j) {
            const int r = kg * 4 + j;
            S[r][wid * 16 + col]      = valid ? acc0[j] * scale : NEG;
            S[r + 16][wid * 16 + col] = valid ? acc1[j] * scale : NEG;
        }
    }
    __syncthreads();

    // ---- P2: per-row partials: 8 threads/row x 8 cols each ----
    {
        const int r = tid >> 3;                 // row 0..31
        const int g = tid & 7;                  // 8-lane group position
        float m = NEG, s = 0.f;
        float v[8]; int ji[8];
        #pragma unroll
        for (int k = 0; k < 8; ++k) { v[k] = NEG; ji[k] = 0x7ffffffe; }

        #pragma unroll
        for (int e = 0; e < 8; ++e) {
            const int c  = g * 8 + e;
            const float x = S[r][c];
            const int  gi = blockIdx.x * 64 + c;
            if (x > -5e29f) {                   // skip invalid-key sentinels
                const float nm = fmaxf(m, x);
                s = s * __expf(m - nm) + __expf(x - nm);
                m = nm;
                top8_insert(v, ji, x, gi);
            }
        }

        // group (m,s) combine over 8 lanes (s==0 guards the NEG cases)
        #pragma unroll
        for (int off = 1; off < 8; off <<= 1) {
            float om = __shfl_xor(m, off), os = __shfl_xor(s, off);
            float M2 = fmaxf(m, om);
            s = s * __expf(m - M2) + os * __expf(om - M2);
            m = M2;
        }

        // group top-8 selection (8 rounds over 8 sorted lists)
        float sel_v[8]; int sel_i[8];
        #pragma unroll
        for (int rr = 0; rr < 8; ++rr) {
            float mv = v[0]; int mi = ji[0];
            #pragma unroll
            for (int off = 1; off < 8; off <<= 1) {
                float ov = __shfl_xor(mv, off);
                int   oi = __shfl_xor(mi, off);
                if (ov > mv || (ov == mv && oi < mi)) { mv = ov; mi = oi; }
            }
            if (v[0] == mv && ji[0] == mi) {    // I won: pop my head
                #pragma unroll
                for (int k = 0; k < 7; ++k) { v[k] = v[k + 1]; ji[k] = ji[k + 1]; }
                v[7] = NEG; ji[7] = 0x7ffffffe;
            }
            sel_v[rr] = mv; sel_i[rr] = mi;
        }

        if (g == 0) {
            const size_t base = (size_t)r * NTB + blockIdx.x;
            pmg[base] = m; psg[base] = s;
            #pragma unroll
            for (int k = 0; k < 8; ++k) {
                cvg[base * 8 + k] = sel_v[k];
                cig[base * 8 + k] = sel_i[k];
            }
        }
    }
}

// ---- K2: per row: merge NTB partials -> top-12 -> exact rescore -----------
__global__ __launch_bounds__(256) void row_merge_kernel(
    const float* __restrict__ pmg, const float* __restrict__ psg,
    const float* __restrict__ cvg, const int* __restrict__ cig,
    const float* __restrict__ q, const float* __restrict__ keys,
    float* __restrict__ out_w, int* __restrict__ tidx, int NTB)
{
    const int b    = blockIdx.x;
    const int tid  = threadIdx.x;
    const int lane = tid & 63;
    const int wid  = tid >> 6;
    const float scale = 0.04419417382415922f;

    __shared__ float lm[4], ls[4], lcv[4][TOPK];
    __shared__ int   lci[4][TOPK];

    // ---- thread-local: combine ~2 tiles' partials ----
    float m = NEG, s = 0.f;
    float v[8]; int ji[8];
    #pragma unroll
    for (int k = 0; k < 8; ++k) { v[k] = NEG; ji[k] = 0x7ffffffe; }

    for (int tb = tid; tb < NTB; tb += 256) {
        const size_t base = (size_t)b * NTB + tb;
        const float pm_t = pmg[base], ps_t = psg[base];
        const float M2 = fmaxf(m, pm_t);
        s = s * __expf(m - M2) + ps_t * __expf(pm_t - M2);
        m = M2;
        #pragma unroll
        for (int k = 0; k < 8; ++k) {
            top8_insert(v, ji, cvg[base * 8 + k], cig[base * 8 + k]);
        }
    }

    // ---- wave-level (m,s) combine ----
    #pragma unroll
    for (int off = 1; off < 64; off <<= 1) {
        float om = __shfl_xor(m, off), os = __shfl_xor(s, off);
        float M2 = fmaxf(m, om);
        s = s * __expf(m - M2) + os * __expf(om - M2);
        m = M2;
    }

    // ---- wave-level top-8 merge: 8 selection rounds ----
    float selv = 0.f; int seli = 0;
    #pragma unroll
    for (int r = 0; r < TOPK; ++r) {
        float mv = v[0]; int mi = ji[0];
        wave_argmax(mv, mi);
        if (v[0] == mv && ji[0] == mi) {       // I won: pop my head
            #pragma unroll
            for (int k = 0; k < TOPK - 1; ++k) { v[k] = v[k + 1]; ji[k] = ji[k + 1]; }
            v[TOPK - 1] = NEG; ji[TOPK - 1] = 0x7ffffffe;
        }
        if (lane == r) { selv = mv; seli = mi; }
    }

    if (lane == 0) { lm[wid] = m; ls[wid] = s; }
    if (lane < TOPK) { lcv[wid][lane] = selv; lci[wid][lane] = seli; }
    __syncthreads();

    if (wid != 0) return;

    // ---- cross-wave combine (all lanes of wave 0 redundantly) ----
    float M = lm[0], S = ls[0];
    #pragma unroll
    for (int cc = 1; cc < 4; ++cc) {
        float M2 = fmaxf(M, lm[cc]);
        S = S * __expf(M - M2) + ls[cc] * __expf(lm[cc] - M2);
        M = M2;
    }

    // ---- 32 candidates -> approx top-12 ----
    float vv = (lane < 32) ? lcv[lane >> 3][lane & 7] : NEG;
    int   ii = (lane < 32) ? lci[lane >> 3][lane & 7] : 0x7ffffffe;
    int   si = 0x7ffffffe;
    #pragma unroll
    for (int r = 0; r < 12; ++r) {
        float mv = vv; int mi = ii;
        wave_argmax(mv, mi);
        if (vv == mv && ii == mi) vv = NEG;
        if (lane == r) si = mi;
    }

    // ---- exact fp32 rescore of the 12 candidates ----
    float4 qa = *reinterpret_cast<const float4*>(q + (size_t)b * DKD + lane * 8);
    float4 qb = *reinterpret_cast<const float4*>(q + (size_t)b * DKD + lane * 8 + 4);
    float exv = NEG;
    #pragma unroll
    for (int r = 0; r < 12; ++r) {
        const int cand = __shfl(si, r);
        const float* kr = keys + (size_t)cand * DKD + lane * 8;
        float4 k1 = *reinterpret_cast<const float4*>(kr);
        float4 k2 = *reinterpret_cast<const float4*>(kr + 4);
        float p = qa.x * k1.x + qa.y * k1.y + qa.z * k1.z + qa.w * k1.w
                + qb.x * k2.x + qb.y * k2.y + qb.z * k2.z + qb.w * k2.w;
        #pragma unroll
        for (int off = 1; off < 64; off <<= 1) p += __shfl_xor(p, off);
        if (lane == r) exv = p * scale;
    }

    // ---- exact top-8 of 12, emit weights (max M cancels num/denom) ----
    float fv = (lane < 12) ? exv : NEG;
    int   fi = (lane < 12) ? si : 0x7ffffffe;
    #pragma unroll
    for (int r = 0; r < TOPK; ++r) {
        float mv = fv; int mi = fi;
        wave_argmax(mv, mi);
        if (fv == mv && fi == mi) fv = NEG;
        if (lane == r) {
            out_w[b * TOPK + r] = __expf(mv - M) / S;
            tidx[b * TOPK + r]  = mi;
        }
    }
}

// ---- K3: gather values rows (4 blocks per output row) ---------------------
__global__ __launch_bounds__(256) void gather_kernel(
    const float* __restrict__ values, const int* __restrict__ idx,
    float* __restrict__ out, int LDV)
{
    const int bk  = blockIdx.x >> 2;
    const int qtr = blockIdx.x & 3;
    const int id = idx[bk];
    const float4* src = reinterpret_cast<const float4*>(values + (size_t)id * LDV);
    float4*       dst = reinterpret_cast<float4*>(out + (size_t)bk * LDV);
    const int n4 = LDV >> 2;                 // 2560
    const int qn = n4 >> 2;                  // 640
    for (int i = qtr * qn + threadIdx.x; i < (qtr + 1) * qn; i += 256)
        dst[i] = src[i];
}

extern "C" void kernel_launch(void* const* d_in, const int* in_sizes, int n_in,
                              void* d_out, int out_size, void* d_ws, size_t ws_size,
                              hipStream_t stream) {
    const float* q      = (const float*)d_in[0];
    const float* keys   = (const float*)d_in[1];
    const float* values = (const float*)d_in[2];

    const int B   = in_sizes[0] / DKD;                 // 32
    const int N   = in_sizes[1] / DKD;                 // 20000
    const int LDV = (int)((long long)in_sizes[2] / N); // 10240
    const int NTB = (N + 63) / 64;                     // 313

    float* out   = (float*)d_out;
    float* out_w = out;
    float* out_v = out + (size_t)B * TOPK;

    char* wsb = (char*)d_ws;
    size_t off = 0;
    float* pmg = (float*)(wsb + off); off += (size_t)B * NTB * sizeof(float);
    float* psg = (float*)(wsb + off); off += (size_t)B * NTB * sizeof(float);
    float* cvg = (float*)(wsb + off); off += (size_t)B * NTB * 8 * sizeof(float);
    int*   cig = (int*)(wsb + off);   off += (size_t)B * NTB * 8 * sizeof(int);
    int*   tidx = (int*)(wsb + off);  off += (size_t)B * TOPK * sizeof(int);

    score_part_kernel<<<NTB, 256, 0, stream>>>(q, keys, pmg, psg, cvg, cig, N, NTB);
    row_merge_kernel<<<B, 256, 0, stream>>>(pmg, psg, cvg, cig, q, keys, out_w, tidx, NTB);
    gather_kernel<<<B * TOPK * 4, 256, 0, stream>>>(values, tidx, out_v, LDV);
}